// Round 1
// baseline (152.464 us; speedup 1.0000x reference)
//
#include <hip/hip_runtime.h>
#include <hip/hip_bf16.h>

#define GAMMA 0.1f
#define ETA   0.3f

// Block = 256 threads (4 waves). Each thread handles 4 rows (lane-strided
// within a 256-row wave chunk so the scalar outputs coalesce). W2 (64x32),
// u/v/b1 (fused W1), b2, ln_w, ln_b staged in LDS; W2 rows consumed as
// same-address broadcast ds_read_b128 (conflict-free), each read amortized
// over 4 rows x 4 cols of FMAs.
__global__ __launch_bounds__(256) void market_impact_kernel(
    const float* __restrict__ os_g, const float* __restrict__ liq_g,
    const float* __restrict__ W1,  const float* __restrict__ b1,
    const float* __restrict__ W2,  const float* __restrict__ b2,
    const float* __restrict__ lnw, const float* __restrict__ lnb,
    float* __restrict__ out, int B)
{
    __shared__ float4 s_w2[512];   // [k][j4] flat: k*8 + j4  (64x32 fp32, 8 KB)
    __shared__ float4 s_uvb[64];   // (u[k], v[k], b1[k], 0)
    __shared__ float4 s_b2[8], s_lnw[8], s_lnb[8];

    const int tid = threadIdx.x;

    // ---- stage params into LDS ----
    {
        const float4* W2v = reinterpret_cast<const float4*>(W2);
        s_w2[tid * 2]     = W2v[tid * 2];
        s_w2[tid * 2 + 1] = W2v[tid * 2 + 1];
        if (tid < 64) {
            // W1 is (3,64) row-major. feats = [perm, temp, perm+temp] =>
            // h = relu(perm*(W1[0]+W1[2]) + temp*(W1[1]+W1[2]) + b1)
            float u = W1[tid] + W1[128 + tid];
            float v = W1[64 + tid] + W1[128 + tid];
            s_uvb[tid] = make_float4(u, v, b1[tid], 0.f);
        }
        if (tid < 8) {
            s_b2[tid]  = reinterpret_cast<const float4*>(b2)[tid];
            s_lnw[tid] = reinterpret_cast<const float4*>(lnw)[tid];
            s_lnb[tid] = reinterpret_cast<const float4*>(lnb)[tid];
        }
    }
    __syncthreads();

    const int lane = tid & 63;
    const int wave = tid >> 6;
    const int wbase = blockIdx.x * 1024 + wave * 256;

    int   r[4];
    bool  ok[4];
    float perm[4], temp[4], tot[4];
    #pragma unroll
    for (int s = 0; s < 4; ++s) {
        r[s]  = wbase + 64 * s + lane;
        ok[s] = r[s] < B;
        float o = ok[s] ? os_g[r[s]]  : 0.f;
        float l = ok[s] ? liq_g[r[s]] : 1.f;
        perm[s] = GAMMA * o / l;                                   // exact div
        temp[s] = ETA * copysignf(sqrtf(fabsf(o)), o) * rsqrtf(l);
        tot[s]  = perm[s] + temp[s];
    }

    // ---- scalar output streams (coalesced) ----
    #pragma unroll
    for (int s = 0; s < 4; ++s) {
        if (ok[s]) {
            out[r[s]]         = perm[s];
            out[B + r[s]]     = temp[s];
            out[2 * B + r[s]] = tot[s];
        }
    }

    // ---- acc = b2 ----
    float acc[4][32];
    #pragma unroll
    for (int j4 = 0; j4 < 8; ++j4) {
        float4 bv = s_b2[j4];
        #pragma unroll
        for (int s = 0; s < 4; ++s) {
            acc[s][j4 * 4 + 0] = bv.x;
            acc[s][j4 * 4 + 1] = bv.y;
            acc[s][j4 * 4 + 2] = bv.z;
            acc[s][j4 * 4 + 3] = bv.w;
        }
    }

    // ---- k-loop: h_k recomputed (3 ops), 128 FMAs per k per thread ----
    #pragma unroll 4
    for (int k = 0; k < 64; ++k) {
        float4 uvb = s_uvb[k];
        float h[4];
        #pragma unroll
        for (int s = 0; s < 4; ++s)
            h[s] = fmaxf(0.f, fmaf(perm[s], uvb.x, fmaf(temp[s], uvb.y, uvb.z)));
        #pragma unroll
        for (int j4 = 0; j4 < 8; ++j4) {
            float4 w = s_w2[k * 8 + j4];
            #pragma unroll
            for (int s = 0; s < 4; ++s) {
                acc[s][j4 * 4 + 0] = fmaf(h[s], w.x, acc[s][j4 * 4 + 0]);
                acc[s][j4 * 4 + 1] = fmaf(h[s], w.y, acc[s][j4 * 4 + 1]);
                acc[s][j4 * 4 + 2] = fmaf(h[s], w.z, acc[s][j4 * 4 + 2]);
                acc[s][j4 * 4 + 3] = fmaf(h[s], w.w, acc[s][j4 * 4 + 3]);
            }
        }
    }

    // ---- LayerNorm(32) + store encoded ----
    float* enc = out + 3 * B;
    #pragma unroll
    for (int s = 0; s < 4; ++s) {
        if (!ok[s]) continue;
        float sum = 0.f;
        #pragma unroll
        for (int j = 0; j < 32; ++j) sum += acc[s][j];
        float mu = sum * 0.03125f;
        float var = 0.f;
        #pragma unroll
        for (int j = 0; j < 32; ++j) {
            float d = acc[s][j] - mu;
            var = fmaf(d, d, var);
        }
        var *= 0.03125f;
        float rstd = rsqrtf(var + 1e-5f);

        float4 o4[8];
        #pragma unroll
        for (int j4 = 0; j4 < 8; ++j4) {
            float4 wv = s_lnw[j4], bv = s_lnb[j4];
            o4[j4].x = fmaf((acc[s][j4 * 4 + 0] - mu) * rstd, wv.x, bv.x);
            o4[j4].y = fmaf((acc[s][j4 * 4 + 1] - mu) * rstd, wv.y, bv.y);
            o4[j4].z = fmaf((acc[s][j4 * 4 + 2] - mu) * rstd, wv.z, bv.z);
            o4[j4].w = fmaf((acc[s][j4 * 4 + 3] - mu) * rstd, wv.w, bv.w);
        }
        float4* ep = reinterpret_cast<float4*>(enc + (long long)r[s] * 32);
        #pragma unroll
        for (int j4 = 0; j4 < 8; ++j4) ep[j4] = o4[j4];
    }
}

extern "C" void kernel_launch(void* const* d_in, const int* in_sizes, int n_in,
                              void* d_out, int out_size, void* d_ws, size_t ws_size,
                              hipStream_t stream) {
    const float* os_g = (const float*)d_in[0];
    const float* liq  = (const float*)d_in[1];
    const float* W1   = (const float*)d_in[2];
    const float* b1   = (const float*)d_in[3];
    const float* W2   = (const float*)d_in[4];
    const float* b2   = (const float*)d_in[5];
    const float* lnw  = (const float*)d_in[6];
    const float* lnb  = (const float*)d_in[7];
    float* out = (float*)d_out;
    const int B = in_sizes[0];

    const int rows_per_block = 256 * 4;
    const int grid = (B + rows_per_block - 1) / rows_per_block;
    market_impact_kernel<<<grid, 256, 0, stream>>>(
        os_g, liq, W1, b1, W2, b2, lnw, lnb, out, B);
}

// Round 2
// 86.083 us; speedup vs baseline: 1.7711x; 1.7711x over previous
//
#include <hip/hip_runtime.h>

#define GAMMA 0.1f
#define ETA   0.3f

typedef __attribute__((ext_vector_type(8))) short short8;
typedef __attribute__((ext_vector_type(4))) float f32x4;

#define ITERS 2   // 64-row chunks per wave

__device__ __forceinline__ short f2bf(float x) {
    // round-to-nearest-even fp32 -> bf16 (payload bits)
    unsigned u = __float_as_uint(x);
    u += 0x7FFFu + ((u >> 16) & 1u);
    return (short)(u >> 16);
}

// Each wave handles ITERS*64 rows. Per 64-row chunk:
//   lane l computes perm/temp/total for row base+l (coalesced stream stores),
//   then 4 m-tiles of 16 rows through MFMA with SWAPPED operands:
//     d = mfma(W2^T_frag, h_frag, d)  -> lane&15 = output ROW, so LayerNorm
//   reduces over only 4 lanes (xor 16,32) and stores are float4.
// h = relu(perm*u + temp*v + b1) with u=W1[0]+W1[2], v=W1[1]+W1[2] (feats rank-2).
// All weights register-resident; no LDS, no barriers.
__global__ __launch_bounds__(256) void market_impact_mfma(
    const float* __restrict__ os_g, const float* __restrict__ liq_g,
    const float* __restrict__ W1,  const float* __restrict__ b1g,
    const float* __restrict__ W2,  const float* __restrict__ b2,
    const float* __restrict__ lnw, const float* __restrict__ lnb,
    float* __restrict__ out, int B)
{
    const int tid  = threadIdx.x;
    const int lane = tid & 63;
    const int g    = lane >> 4;   // k-group (0..3)
    const int c    = lane & 15;   // A-operand row = out-col block idx; B col = data row

    // ---- one-time per-lane weights (global, tiny, cached) ----
    float u[16], v[16], bb[16];
    #pragma unroll
    for (int kc = 0; kc < 2; ++kc)
        #pragma unroll
        for (int j = 0; j < 8; ++j) {
            int k = kc * 32 + g * 8 + j;
            float w0 = W1[k], w1 = W1[64 + k], w2r = W1[128 + k];
            u[kc * 8 + j]  = w0 + w2r;
            v[kc * 8 + j]  = w1 + w2r;
            bb[kc * 8 + j] = b1g[k];
        }

    // W2^T fragments: A-operand for swapped mfma. lane m=c is the OUTPUT col
    // within block cc; element j <-> k = kc*32 + g*8 + j.
    short8 wfrag[2][2];
    #pragma unroll
    for (int kc = 0; kc < 2; ++kc)
        #pragma unroll
        for (int cc = 0; cc < 2; ++cc) {
            short8 t;
            #pragma unroll
            for (int j = 0; j < 8; ++j) {
                int k = kc * 32 + g * 8 + j;
                t[j] = f2bf(W2[k * 32 + cc * 16 + c]);
            }
            wfrag[kc][cc] = t;
        }

    // epilogue constants: this lane's output cols are cc*16 + g*4 + reg
    float b2a[8], lnwa[8], lnba[8];
    #pragma unroll
    for (int cc = 0; cc < 2; ++cc) {
        float4 bq = *reinterpret_cast<const float4*>(b2  + cc * 16 + g * 4);
        float4 wq = *reinterpret_cast<const float4*>(lnw + cc * 16 + g * 4);
        float4 bl = *reinterpret_cast<const float4*>(lnb + cc * 16 + g * 4);
        b2a[cc*4+0] = bq.x; b2a[cc*4+1] = bq.y; b2a[cc*4+2] = bq.z; b2a[cc*4+3] = bq.w;
        lnwa[cc*4+0] = wq.x; lnwa[cc*4+1] = wq.y; lnwa[cc*4+2] = wq.z; lnwa[cc*4+3] = wq.w;
        lnba[cc*4+0] = bl.x; lnba[cc*4+1] = bl.y; lnba[cc*4+2] = bl.z; lnba[cc*4+3] = bl.w;
    }

    const long long wid = (long long)blockIdx.x * 4 + (tid >> 6);
    float* enc = out + 3LL * B;

    #pragma unroll 1
    for (int it = 0; it < ITERS; ++it) {
        long long base = (wid * ITERS + it) * 64;
        if (base >= B) break;                      // wave-uniform

        int r  = (int)base + lane;
        bool ok = r < B;
        float o  = ok ? os_g[r]  : 0.f;
        float lq = ok ? liq_g[r] : 1.f;
        float perm = GAMMA * o / lq;
        float temp = ETA * copysignf(sqrtf(fabsf(o)), o) * rsqrtf(lq);
        float tot  = perm + temp;
        if (ok) {
            out[r]         = perm;
            out[B + r]     = temp;
            out[2 * B + r] = tot;
        }

        #pragma unroll
        for (int mt = 0; mt < 4; ++mt) {
            // B-operand: h for row base + mt*16 + c, k = kc*32 + g*8 + j
            float pm = __shfl(perm, mt * 16 + c);
            float tm = __shfl(temp, mt * 16 + c);
            short8 a0, a1;
            #pragma unroll
            for (int j = 0; j < 8; ++j) {
                float h0 = fmaxf(0.f, fmaf(pm, u[j],     fmaf(tm, v[j],     bb[j])));
                float h1 = fmaxf(0.f, fmaf(pm, u[8 + j], fmaf(tm, v[8 + j], bb[8 + j])));
                a0[j] = f2bf(h0);
                a1[j] = f2bf(h1);
            }

            f32x4 d0 = {0.f, 0.f, 0.f, 0.f};
            f32x4 d1 = {0.f, 0.f, 0.f, 0.f};
            d0 = __builtin_amdgcn_mfma_f32_16x16x32_bf16(wfrag[0][0], a0, d0, 0, 0, 0);
            d0 = __builtin_amdgcn_mfma_f32_16x16x32_bf16(wfrag[1][0], a1, d0, 0, 0, 0);
            d1 = __builtin_amdgcn_mfma_f32_16x16x32_bf16(wfrag[0][1], a0, d1, 0, 0, 0);
            d1 = __builtin_amdgcn_mfma_f32_16x16x32_bf16(wfrag[1][1], a1, d1, 0, 0, 0);

            // x = d + b2 ; lane holds row (base+mt*16+c), cols cc*16+g*4+reg
            float x[8];
            #pragma unroll
            for (int reg = 0; reg < 4; ++reg) {
                x[reg]     = d0[reg] + b2a[reg];
                x[4 + reg] = d1[reg] + b2a[4 + reg];
            }
            float s = 0.f, q = 0.f;
            #pragma unroll
            for (int j = 0; j < 8; ++j) { s += x[j]; q = fmaf(x[j], x[j], q); }
            s += __shfl_xor(s, 16); s += __shfl_xor(s, 32);
            q += __shfl_xor(q, 16); q += __shfl_xor(q, 32);
            float mu   = s * 0.03125f;
            float var  = fmaf(q, 0.03125f, -mu * mu);
            float rstd = rsqrtf(var + 1e-5f);

            int row = (int)base + mt * 16 + c;
            if (row < B) {
                float4 o0, o1;
                o0.x = fmaf((x[0] - mu) * rstd, lnwa[0], lnba[0]);
                o0.y = fmaf((x[1] - mu) * rstd, lnwa[1], lnba[1]);
                o0.z = fmaf((x[2] - mu) * rstd, lnwa[2], lnba[2]);
                o0.w = fmaf((x[3] - mu) * rstd, lnwa[3], lnba[3]);
                o1.x = fmaf((x[4] - mu) * rstd, lnwa[4], lnba[4]);
                o1.y = fmaf((x[5] - mu) * rstd, lnwa[5], lnba[5]);
                o1.z = fmaf((x[6] - mu) * rstd, lnwa[6], lnba[6]);
                o1.w = fmaf((x[7] - mu) * rstd, lnwa[7], lnba[7]);
                float* rp = enc + (long long)row * 32;
                *reinterpret_cast<float4*>(rp + g * 4)      = o0;
                *reinterpret_cast<float4*>(rp + 16 + g * 4) = o1;
            }
        }
    }
}

extern "C" void kernel_launch(void* const* d_in, const int* in_sizes, int n_in,
                              void* d_out, int out_size, void* d_ws, size_t ws_size,
                              hipStream_t stream) {
    const float* os_g = (const float*)d_in[0];
    const float* liq  = (const float*)d_in[1];
    const float* W1   = (const float*)d_in[2];
    const float* b1   = (const float*)d_in[3];
    const float* W2   = (const float*)d_in[4];
    const float* b2   = (const float*)d_in[5];
    const float* lnw  = (const float*)d_in[6];
    const float* lnb  = (const float*)d_in[7];
    float* out = (float*)d_out;
    const int B = in_sizes[0];

    const int rows_per_block = 4 * ITERS * 64;   // 4 waves * ITERS chunks * 64 rows
    const int grid = (B + rows_per_block - 1) / rows_per_block;
    market_impact_mfma<<<grid, 256, 0, stream>>>(
        os_g, liq, W1, b1, W2, b2, lnw, lnb, out, B);
}